// Round 9
// baseline (4603.776 us; speedup 1.0000x reference)
//
#include <hip/hip_runtime.h>
#include <hip/hip_bf16.h>
#include <math.h>

// QRNN quantum-circuit simulator, 16 qubits, B=256, T=32.
// State: float2 S[bb][s], s = h*256 + l; qubit j<8 <-> bit j of l, qubit
// 8+k <-> bit k of h. bb = batch within the current 128-batch chunk (the two
// chunks reuse the same 64MB workspace -> L3-resident).
//
// Schedule (verified r6/r8):
//   H<INIT>: build (A_0 (x) B)|0>, D, B
//   L_m:     A_{2m+1}, D, A_{2m+2}     (m=0..14)
//   H:       B, D, B
//   L<FIN>:  A_31, expectation -> out
//
// r8 lesson: shfl-based gates are LDS-pipe-bound (2 ds ops per amp per
// lane-gate; ~24 ds/amp-slot ~= 30us/CU >> 16us HBM floor). This version
// makes ALL gates register-local: 16 amps/thread (4 in-thread bits), one
// XOR-swizzled LDS transpose (c(v)=v^((v>>4)&15), row stride 258) switches
// which 4 bits are in-thread. All gate-phase LDS accesses are at the b64
// conflict floor (4 words/bank) by construction.

#define DEV static __device__ __forceinline__

DEV float2 cmul(float2 a, float2 b){ return make_float2(a.x*b.x - a.y*b.y, a.x*b.y + a.y*b.x); }
DEV float2 cadd(float2 a, float2 b){ return make_float2(a.x+b.x, a.y+b.y); }
DEV float2 cscale(float s, float2 a){ return make_float2(s*a.x, s*a.y); }
DEV float2 cfma2(float2 u0, float2 a, float2 u1, float2 b){
  return make_float2(u0.x*a.x - u0.y*a.y + u1.x*b.x - u1.y*b.y,
                     u0.x*a.y + u0.y*a.x + u1.x*b.y + u1.y*b.x);
}
DEV void gpair(float2 &A, float2 &B, float2 u00, float2 u01, float2 u10, float2 u11){
  float2 na = cfma2(u00, A, u01, B);
  float2 nb = cfma2(u10, A, u11, B);
  A = na; B = nb;
}
// XOR swizzle: bijective column for value v in 0..255
DEV int swz(int v){ return v ^ ((v >> 4) & 15); }

// gate on in-thread bit B of a 16-amp register array
template<int B>
DEV void gate16(float2* A, float2 u00, float2 u01, float2 u10, float2 u11){
  #pragma unroll
  for (int i=0;i<16;i++)
    if ((i & B) == 0) gpair(A[i], A[i|B], u00, u01, u10, u11);
}

// ---------- setup: fused gates G_j, diagonal tables, B|0> table, out init ----
__global__ __launch_bounds__(256) void k_setup(
    const float* __restrict__ w, const float* __restrict__ b_out,
    float* __restrict__ out, float2* __restrict__ G,
    float2* __restrict__ PHL, float2* __restrict__ PHB,
    float2* __restrict__ PH0){
  __shared__ float2 Gs[64];
  int tid = threadIdx.x;
  if (tid < 16){
    int j = tid;
    float a0 = w[j*4+0], a1 = w[j*4+1], a2 = w[j*4+2];
    float c0 = cosf(0.5f*a0), s0 = sinf(0.5f*a0);
    float c1 = cosf(0.5f*a1), s1 = sinf(0.5f*a1);
    float c2 = cosf(0.5f*a2), s2 = sinf(0.5f*a2);
    float2 m00 = make_float2( c0*c1, -c0*s1);   // M = RZ(a1)*RX(a0)
    float2 m01 = make_float2(-s0*s1, -s0*c1);
    float2 m10 = make_float2( s0*s1, -s0*c1);
    float2 m11 = make_float2( c0*c1,  c0*s1);
    float2 mi2 = make_float2(0.f, -s2);
    float2 g0 = cadd(cscale(c2,m00), cmul(mi2,m10));   // G = RX(a2)*M
    float2 g1 = cadd(cscale(c2,m01), cmul(mi2,m11));
    float2 g2 = cadd(cmul(mi2,m00), cscale(c2,m10));
    float2 g3 = cadd(cmul(mi2,m01), cscale(c2,m11));
    Gs[j*4+0]=g0; Gs[j*4+1]=g1; Gs[j*4+2]=g2; Gs[j*4+3]=g3;
    G[j*4+0]=g0;  G[j*4+1]=g1;  G[j*4+2]=g2;  G[j*4+3]=g3;
  }
  __syncthreads();
  { // PHL[l]: chain edges (0,1)..(6,7), weight w[j+1,3]
    int l = tid; float phi = 0.f;
    for (int j=0;j<7;j++){
      float v = w[(j+1)*4+3];
      int u = ((l>>j)^(l>>(j+1)))&1;
      phi += -0.5f*v*(1.f-2.f*(float)u);
    }
    PHL[l] = make_float2(cosf(phi), sinf(phi));
  }
  // PHB[c][h]: edges (8,9)..(14,15) + cross (7,8)[w8] and (15,0)[w0];
  // c = bit0(l) | bit7(l)<<1
  for (int c=0;c<4;c++){
    int h = tid;
    float z0 = 1.f-2.f*(float)(c&1);
    float z7 = 1.f-2.f*(float)((c>>1)&1);
    float phi = 0.f;
    for (int k=0;k<7;k++){
      float v = w[(9+k)*4+3];
      int u = ((h>>k)^(h>>(k+1)))&1;
      phi += -0.5f*v*(1.f-2.f*(float)u);
    }
    phi += -0.5f*w[8*4+3]*z7*(1.f-2.f*(float)(h&1));
    phi += -0.5f*w[0*4+3]*(1.f-2.f*(float)((h>>7)&1))*z0;
    PHB[c*256+h] = make_float2(cosf(phi), sinf(phi));
  }
  { // PH0[h] = amplitude of B|0>_high at h
    float2 p = make_float2(1.f, 0.f);
    #pragma unroll
    for (int k=0;k<8;k++) p = cmul(p, Gs[(8+k)*4 + 2*((tid>>k)&1)]);
    PH0[tid] = p;
  }
  out[tid] = b_out[0];
}

// ---------- TypeL: A_t1 [, D, A_{t1+1}] on low qubits ----------------------
// Block: bb (low 7 bits of blockIdx -> XCD locality) + h-tile of 16 h.
// Tile in LDS: lds[dh][swz(l)], stride 258. Thread (dh,g) holds 16 amps:
//   layout A: l = k + 16g (in-thread l0-3);  layout B: l = g + 16k (l4-7).
template<bool FINAL>
__global__ __launch_bounds__(256, 4) void k_stepL(
    const float* __restrict__ x, const float2* __restrict__ G,
    const float2* __restrict__ PHL, const float2* __restrict__ PHB,
    const float* __restrict__ w_out, float2* __restrict__ S,
    float* __restrict__ out, int t1, int b0){
  const int bb   = blockIdx.x & 127;
  const int tile = blockIdx.x >> 7;
  const int tid  = threadIdx.x;
  const int lane = tid & 63;
  const int wv   = tid >> 6;
  __shared__ float2 lds[16*258];
  __shared__ float2 V[2][32];
  __shared__ float red[4];
  if (tid < (FINAL ? 8 : 16)){
    int set = tid >> 3, j = tid & 7;
    float xv = x[(b0 + bb)*32 + t1 + set];
    float cc = sqrtf(0.5f*(1.f+xv));            // cos(arccos(x)/2)
    float sn = sqrtf(0.5f*(1.f-xv));
    float2 g00=G[j*4+0], g01=G[j*4+1], g10=G[j*4+2], g11=G[j*4+3];
    V[set][j*4+0] = cadd(cscale( cc,g00), cscale(sn,g01));
    V[set][j*4+1] = cadd(cscale(-sn,g00), cscale(cc,g01));
    V[set][j*4+2] = cadd(cscale( cc,g10), cscale(sn,g11));
    V[set][j*4+3] = cadd(cscale(-sn,g10), cscale(cc,g11));
  }
  float2* Sb = S + ((size_t)bb << 16);
  const float4* Sr = (const float4*)Sb;
  #pragma unroll
  for (int it=0; it<8; ++it){                   // stage in (1KB/wave segments)
    int idx = it*256 + tid;
    int lp = idx & 127, dhi = idx >> 7;
    float4 v = Sr[(size_t)(tile*16 + dhi)*128 + lp];
    int c = swz(2*lp);
    lds[dhi*258 + c]     = make_float2(v.x, v.y);
    lds[dhi*258 + (c^1)] = make_float2(v.z, v.w);
  }
  __syncthreads();
  const int dh   = (wv<<2) | (lane>>4);
  const int g    = lane & 15;
  const int rowb = dh*258;
  float2 A[16];
  #pragma unroll
  for (int k=0;k<16;k++) A[k] = lds[rowb + swz(k + 16*g)];   // layout A
  { const float2* Vp = &V[0][0];                // A_t1 gates l0..l3
    gate16<1>(A, Vp[0], Vp[1], Vp[2], Vp[3]);
    gate16<2>(A, Vp[4], Vp[5], Vp[6], Vp[7]);
    gate16<4>(A, Vp[8], Vp[9], Vp[10],Vp[11]);
    gate16<8>(A, Vp[12],Vp[13],Vp[14],Vp[15]); }
  #pragma unroll
  for (int k=0;k<16;k++) lds[rowb + swz(k + 16*g)] = A[k];
  __syncthreads();
  #pragma unroll
  for (int k=0;k<16;k++) A[k] = lds[rowb + swz(g + 16*k)];   // layout B
  { const float2* Vp = &V[0][0];                // A_t1 gates l4..l7
    gate16<1>(A, Vp[16],Vp[17],Vp[18],Vp[19]);
    gate16<2>(A, Vp[20],Vp[21],Vp[22],Vp[23]);
    gate16<4>(A, Vp[24],Vp[25],Vp[26],Vp[27]);
    gate16<8>(A, Vp[28],Vp[29],Vp[30],Vp[31]); }
  if (!FINAL){
    // diagonal D: l = g + 16k; cls = bit0(l) | bit7(l)<<1 = (g&1) | (k>>3)<<1
    const int h = tile*16 + dh;
    float2 phb0 = PHB[(g&1)*256 + h];
    float2 phb1 = PHB[((g&1)|2)*256 + h];
    #pragma unroll
    for (int k=0;k<16;k++){
      float2 wk = cmul(PHL[g + 16*k], (k<8) ? phb0 : phb1);
      A[k] = cmul(A[k], wk);
    }
    { const float2* Vp = &V[1][0];              // A_{t1+1} gates l4..l7
      gate16<1>(A, Vp[16],Vp[17],Vp[18],Vp[19]);
      gate16<2>(A, Vp[20],Vp[21],Vp[22],Vp[23]);
      gate16<4>(A, Vp[24],Vp[25],Vp[26],Vp[27]);
      gate16<8>(A, Vp[28],Vp[29],Vp[30],Vp[31]); }
    #pragma unroll
    for (int k=0;k<16;k++) lds[rowb + swz(g + 16*k)] = A[k];
    __syncthreads();
    #pragma unroll
    for (int k=0;k<16;k++) A[k] = lds[rowb + swz(k + 16*g)]; // layout A
    { const float2* Vp = &V[1][0];              // A_{t1+1} gates l0..l3
      gate16<1>(A, Vp[0], Vp[1], Vp[2], Vp[3]);
      gate16<2>(A, Vp[4], Vp[5], Vp[6], Vp[7]);
      gate16<4>(A, Vp[8], Vp[9], Vp[10],Vp[11]);
      gate16<8>(A, Vp[12],Vp[13],Vp[14],Vp[15]); }
    #pragma unroll
    for (int k=0;k<16;k++) lds[rowb + swz(k + 16*g)] = A[k];
    __syncthreads();
    float4* Sw = (float4*)Sb;
    #pragma unroll
    for (int it=0; it<8; ++it){                 // stage out
      int idx = it*256 + tid;
      int lp = idx & 127, dhi = idx >> 7;
      int c = swz(2*lp);
      float2 v0 = lds[dhi*258 + c];
      float2 v1 = lds[dhi*258 + (c^1)];
      Sw[(size_t)(tile*16 + dhi)*128 + lp] = make_float4(v0.x,v0.y,v1.x,v1.y);
    }
  } else {
    // expectation: l = g + 16k; Q(l) = sum_j w_out[j]*(1-2 bit_j(l))
    float qg = 0.f;
    #pragma unroll
    for (int j=0;j<4;j++) qg += w_out[j] * (1.f - 2.f*(float)((g>>j)&1));
    float w4 = w_out[4], w5 = w_out[5], w6 = w_out[6], w7 = w_out[7];
    float acc = 0.f;
    #pragma unroll
    for (int k=0;k<16;k++){
      float qk = ((k&1)? -w4:w4) + ((k&2)? -w5:w5)
               + ((k&4)? -w6:w6) + ((k&8)? -w7:w7);
      acc += (qg + qk) * (A[k].x*A[k].x + A[k].y*A[k].y);
    }
    #pragma unroll
    for (int m=1;m<64;m<<=1) acc += __shfl_xor(acc, m, 64);
    if (lane == 0) red[wv] = acc;
    __syncthreads();
    if (tid == 0) atomicAdd(out + b0 + bb, red[0]+red[1]+red[2]+red[3]);
  }
}

// ---------- TypeH: B, D, B on high qubits ----------------------------------
// Block: bb + l-tile of 16 l. Tile in LDS: lds[dl][swz(h)], stride 258.
// Thread (dl,g): layout A: h = k + 16g (in-thread h0-3); B: h = g + 16k.
// INIT builds (A_0 (x) B)|0> = Pl(l)*PH0[h] directly in layout B regs.
template<bool INIT>
__global__ __launch_bounds__(256, 4) void k_stepH(
    const float* __restrict__ x, const float2* __restrict__ G,
    const float2* __restrict__ PHL, const float2* __restrict__ PHB,
    const float2* __restrict__ PH0, float2* __restrict__ S, int b0){
  const int bb = blockIdx.x & 127;
  const int lt = blockIdx.x >> 7;
  const int l0 = lt*16;
  const int tid = threadIdx.x, lane = tid & 63, wv = tid >> 6;
  __shared__ float2 lds[16*258];
  __shared__ float2 V[32];
  const int dl   = (wv<<2) | (lane>>4);
  const int g    = lane & 15;
  const int rowb = dl*258;
  const float2* Gh = G + 32;
  float2 A[16];
  float2* Sb = S + ((size_t)bb << 16);
  if (INIT){
    if (tid < 8){
      int j = tid;
      float xv = x[(b0 + bb)*32 + 0];
      float cc = sqrtf(0.5f*(1.f+xv));
      float sn = sqrtf(0.5f*(1.f-xv));
      float2 g00=G[j*4+0], g01=G[j*4+1], g10=G[j*4+2], g11=G[j*4+3];
      V[j*4+0] = cadd(cscale(cc,g00), cscale(sn,g01));   // V[bit=0][0]
      V[j*4+2] = cadd(cscale(cc,g10), cscale(sn,g11));   // V[bit=1][0]
    }
    __syncthreads();
    const int l = l0 + dl;
    float2 Pl = make_float2(1.f, 0.f);
    #pragma unroll
    for (int j=0;j<8;j++) Pl = cmul(Pl, V[j*4 + 2*((l>>j)&1)]);
    const int cls = (l&1) | (((l>>7)&1)<<1);
    float2 phl = PHL[l];
    #pragma unroll
    for (int k=0;k<16;k++){                     // build in layout B + D
      float2 amp = cmul(Pl, PH0[g + 16*k]);
      A[k] = cmul(amp, cmul(phl, PHB[cls*256 + g + 16*k]));
    }
    gate16<1>(A, Gh[16],Gh[17],Gh[18],Gh[19]);  // h4..h7
    gate16<2>(A, Gh[20],Gh[21],Gh[22],Gh[23]);
    gate16<4>(A, Gh[24],Gh[25],Gh[26],Gh[27]);
    gate16<8>(A, Gh[28],Gh[29],Gh[30],Gh[31]);
    #pragma unroll
    for (int k=0;k<16;k++) lds[rowb + swz(g + 16*k)] = A[k];
    __syncthreads();
    #pragma unroll
    for (int k=0;k<16;k++) A[k] = lds[rowb + swz(k + 16*g)];
    gate16<1>(A, Gh[0], Gh[1], Gh[2], Gh[3]);   // h0..h3
    gate16<2>(A, Gh[4], Gh[5], Gh[6], Gh[7]);
    gate16<4>(A, Gh[8], Gh[9], Gh[10],Gh[11]);
    gate16<8>(A, Gh[12],Gh[13],Gh[14],Gh[15]);
    #pragma unroll
    for (int k=0;k<16;k++) lds[rowb + swz(k + 16*g)] = A[k];
    __syncthreads();
  } else {
    const float4* Sr = (const float4*)Sb;
    #pragma unroll
    for (int it=0; it<8; ++it){                 // stage in (128B segments)
      int idx = it*256 + tid;
      int q = idx & 7, h = idx >> 3;
      float4 v = Sr[(size_t)h*128 + (l0>>1) + q];
      int c = swz(h);
      lds[(2*q)*258 + c]   = make_float2(v.x, v.y);
      lds[(2*q+1)*258 + c] = make_float2(v.z, v.w);
    }
    __syncthreads();
    #pragma unroll
    for (int k=0;k<16;k++) A[k] = lds[rowb + swz(k + 16*g)]; // layout A
    gate16<1>(A, Gh[0], Gh[1], Gh[2], Gh[3]);   // sweep1: h0..h3
    gate16<2>(A, Gh[4], Gh[5], Gh[6], Gh[7]);
    gate16<4>(A, Gh[8], Gh[9], Gh[10],Gh[11]);
    gate16<8>(A, Gh[12],Gh[13],Gh[14],Gh[15]);
    #pragma unroll
    for (int k=0;k<16;k++) lds[rowb + swz(k + 16*g)] = A[k];
    __syncthreads();
    #pragma unroll
    for (int k=0;k<16;k++) A[k] = lds[rowb + swz(g + 16*k)]; // layout B
    gate16<1>(A, Gh[16],Gh[17],Gh[18],Gh[19]);  // sweep1: h4..h7
    gate16<2>(A, Gh[20],Gh[21],Gh[22],Gh[23]);
    gate16<4>(A, Gh[24],Gh[25],Gh[26],Gh[27]);
    gate16<8>(A, Gh[28],Gh[29],Gh[30],Gh[31]);
    { // diagonal D: h = g + 16k
      const int l = l0 + dl;
      const int cls = (l&1) | (((l>>7)&1)<<1);
      float2 phl = PHL[l];
      #pragma unroll
      for (int k=0;k<16;k++)
        A[k] = cmul(A[k], cmul(phl, PHB[cls*256 + g + 16*k]));
    }
    gate16<1>(A, Gh[16],Gh[17],Gh[18],Gh[19]);  // sweep2: h4..h7
    gate16<2>(A, Gh[20],Gh[21],Gh[22],Gh[23]);
    gate16<4>(A, Gh[24],Gh[25],Gh[26],Gh[27]);
    gate16<8>(A, Gh[28],Gh[29],Gh[30],Gh[31]);
    #pragma unroll
    for (int k=0;k<16;k++) lds[rowb + swz(g + 16*k)] = A[k];
    __syncthreads();
    #pragma unroll
    for (int k=0;k<16;k++) A[k] = lds[rowb + swz(k + 16*g)]; // layout A
    gate16<1>(A, Gh[0], Gh[1], Gh[2], Gh[3]);   // sweep2: h0..h3
    gate16<2>(A, Gh[4], Gh[5], Gh[6], Gh[7]);
    gate16<4>(A, Gh[8], Gh[9], Gh[10],Gh[11]);
    gate16<8>(A, Gh[12],Gh[13],Gh[14],Gh[15]);
    #pragma unroll
    for (int k=0;k<16;k++) lds[rowb + swz(k + 16*g)] = A[k];
    __syncthreads();
  }
  float4* Sw = (float4*)Sb;
  #pragma unroll
  for (int it=0; it<8; ++it){                   // stage out
    int idx = it*256 + tid;
    int q = idx & 7, h = idx >> 3;
    int c = swz(h);
    float2 v0 = lds[(2*q)*258 + c];
    float2 v1 = lds[(2*q+1)*258 + c];
    Sw[(size_t)h*128 + (l0>>1) + q] = make_float4(v0.x,v0.y,v1.x,v1.y);
  }
}

extern "C" void kernel_launch(void* const* d_in, const int* in_sizes, int n_in,
                              void* d_out, int out_size, void* d_ws, size_t ws_size,
                              hipStream_t stream){
  const float* x     = (const float*)d_in[0];   // [256,32]
  const float* w     = (const float*)d_in[1];   // [16,4]
  const float* w_out = (const float*)d_in[2];   // [1,8]
  const float* b_out = (const float*)d_in[3];   // [1]
  float* out = (float*)d_out;                   // [256]

  const size_t S_BYTES = (size_t)128 * 65536 * sizeof(float2);  // 64 MB chunk
  const size_t NEED = S_BYTES + (64+256+1024+256)*sizeof(float2);
  if (ws_size < NEED) return;

  float2* S   = (float2*)d_ws;
  float2* G   = (float2*)((char*)d_ws + S_BYTES);  // 64 entries
  float2* PHL = G + 64;                            // 256 entries
  float2* PHB = PHL + 256;                         // 1024 entries
  float2* PH0 = PHB + 1024;                        // 256 entries

  k_setup<<<1,256,0,stream>>>(w, b_out, out, G, PHL, PHB, PH0);
  for (int c=0;c<2;c++){
    const int b0 = c*128;
    k_stepH<true><<<2048,256,0,stream>>>(x, G, PHL, PHB, PH0, S, b0);
    for (int m=0;m<15;m++){
      k_stepL<false><<<2048,256,0,stream>>>(x, G, PHL, PHB, w_out, S, out, 2*m+1, b0);
      k_stepH<false><<<2048,256,0,stream>>>(x, G, PHL, PHB, PH0, S, b0);
    }
    k_stepL<true><<<2048,256,0,stream>>>(x, G, PHL, PHB, w_out, S, out, 31, b0);
  }
}

// Round 10
// 4211.400 us; speedup vs baseline: 1.0932x; 1.0932x over previous
//
#include <hip/hip_runtime.h>
#include <hip/hip_bf16.h>
#include <math.h>

// QRNN quantum-circuit simulator, 16 qubits, B=256, T=32.
// State: float2 S[bb][s], s = h*256 + l; qubit j<8 <-> bit j of l, qubit
// 8+k <-> bit k of h. bb = batch within the current 128-batch chunk (the two
// chunks reuse the same 64MB workspace -> L3-resident).
//
// Schedule (verified r6/r8):
//   H<INIT>: build (A_0 (x) B)|0>, D, B
//   L_m:     A_{2m+1}, D, A_{2m+2}     (m=0..14)
//   H:       B, D, B
//   L<FIN>:  A_31, expectation -> out
//
// r9 lesson: blockIdx mapping MUST keep the 16 l-tiles of one batch adjacent
// (bb = blockIdx>>4, tile = blockIdx&15). With bb in the low bits, tiles
// sharing 2KB rows run far apart -> L2 evicts partially-used 128B-interleaved
// lines -> WRITE_SIZE 64->164MB, FETCH 32->84MB, stepH 2.5x slower. This
// version = r9's register-local gates (16 amps/thread, XOR-swizzled LDS
// transpose, all gate-phase LDS at the b64 4-words/bank floor) + r8 mapping.

#define DEV static __device__ __forceinline__

DEV float2 cmul(float2 a, float2 b){ return make_float2(a.x*b.x - a.y*b.y, a.x*b.y + a.y*b.x); }
DEV float2 cadd(float2 a, float2 b){ return make_float2(a.x+b.x, a.y+b.y); }
DEV float2 cscale(float s, float2 a){ return make_float2(s*a.x, s*a.y); }
DEV float2 cfma2(float2 u0, float2 a, float2 u1, float2 b){
  return make_float2(u0.x*a.x - u0.y*a.y + u1.x*b.x - u1.y*b.y,
                     u0.x*a.y + u0.y*a.x + u1.x*b.y + u1.y*b.x);
}
DEV void gpair(float2 &A, float2 &B, float2 u00, float2 u01, float2 u10, float2 u11){
  float2 na = cfma2(u00, A, u01, B);
  float2 nb = cfma2(u10, A, u11, B);
  A = na; B = nb;
}
// XOR swizzle: bijective column for value v in 0..255
DEV int swz(int v){ return v ^ ((v >> 4) & 15); }

// gate on in-thread bit B of a 16-amp register array
template<int B>
DEV void gate16(float2* A, float2 u00, float2 u01, float2 u10, float2 u11){
  #pragma unroll
  for (int i=0;i<16;i++)
    if ((i & B) == 0) gpair(A[i], A[i|B], u00, u01, u10, u11);
}

// ---------- setup: fused gates G_j, diagonal tables, B|0> table, out init ----
__global__ __launch_bounds__(256) void k_setup(
    const float* __restrict__ w, const float* __restrict__ b_out,
    float* __restrict__ out, float2* __restrict__ G,
    float2* __restrict__ PHL, float2* __restrict__ PHB,
    float2* __restrict__ PH0){
  __shared__ float2 Gs[64];
  int tid = threadIdx.x;
  if (tid < 16){
    int j = tid;
    float a0 = w[j*4+0], a1 = w[j*4+1], a2 = w[j*4+2];
    float c0 = cosf(0.5f*a0), s0 = sinf(0.5f*a0);
    float c1 = cosf(0.5f*a1), s1 = sinf(0.5f*a1);
    float c2 = cosf(0.5f*a2), s2 = sinf(0.5f*a2);
    float2 m00 = make_float2( c0*c1, -c0*s1);   // M = RZ(a1)*RX(a0)
    float2 m01 = make_float2(-s0*s1, -s0*c1);
    float2 m10 = make_float2( s0*s1, -s0*c1);
    float2 m11 = make_float2( c0*c1,  c0*s1);
    float2 mi2 = make_float2(0.f, -s2);
    float2 g0 = cadd(cscale(c2,m00), cmul(mi2,m10));   // G = RX(a2)*M
    float2 g1 = cadd(cscale(c2,m01), cmul(mi2,m11));
    float2 g2 = cadd(cmul(mi2,m00), cscale(c2,m10));
    float2 g3 = cadd(cmul(mi2,m01), cscale(c2,m11));
    Gs[j*4+0]=g0; Gs[j*4+1]=g1; Gs[j*4+2]=g2; Gs[j*4+3]=g3;
    G[j*4+0]=g0;  G[j*4+1]=g1;  G[j*4+2]=g2;  G[j*4+3]=g3;
  }
  __syncthreads();
  { // PHL[l]: chain edges (0,1)..(6,7), weight w[j+1,3]
    int l = tid; float phi = 0.f;
    for (int j=0;j<7;j++){
      float v = w[(j+1)*4+3];
      int u = ((l>>j)^(l>>(j+1)))&1;
      phi += -0.5f*v*(1.f-2.f*(float)u);
    }
    PHL[l] = make_float2(cosf(phi), sinf(phi));
  }
  // PHB[c][h]: edges (8,9)..(14,15) + cross (7,8)[w8] and (15,0)[w0];
  // c = bit0(l) | bit7(l)<<1
  for (int c=0;c<4;c++){
    int h = tid;
    float z0 = 1.f-2.f*(float)(c&1);
    float z7 = 1.f-2.f*(float)((c>>1)&1);
    float phi = 0.f;
    for (int k=0;k<7;k++){
      float v = w[(9+k)*4+3];
      int u = ((h>>k)^(h>>(k+1)))&1;
      phi += -0.5f*v*(1.f-2.f*(float)u);
    }
    phi += -0.5f*w[8*4+3]*z7*(1.f-2.f*(float)(h&1));
    phi += -0.5f*w[0*4+3]*(1.f-2.f*(float)((h>>7)&1))*z0;
    PHB[c*256+h] = make_float2(cosf(phi), sinf(phi));
  }
  { // PH0[h] = amplitude of B|0>_high at h
    float2 p = make_float2(1.f, 0.f);
    #pragma unroll
    for (int k=0;k<8;k++) p = cmul(p, Gs[(8+k)*4 + 2*((tid>>k)&1)]);
    PH0[tid] = p;
  }
  out[tid] = b_out[0];
}

// ---------- TypeL: A_t1 [, D, A_{t1+1}] on low qubits ----------------------
// grid: bb = blockIdx>>4, tile = blockIdx&15 (adjacent blocks share rows).
// Tile in LDS: lds[dh][swz(l)], stride 258. Thread (dh,g) holds 16 amps:
//   layout A: l = k + 16g (in-thread l0-3);  layout B: l = g + 16k (l4-7).
template<bool FINAL>
__global__ __launch_bounds__(256, 4) void k_stepL(
    const float* __restrict__ x, const float2* __restrict__ G,
    const float2* __restrict__ PHL, const float2* __restrict__ PHB,
    const float* __restrict__ w_out, float2* __restrict__ S,
    float* __restrict__ out, int t1, int b0){
  const int bb   = blockIdx.x >> 4;
  const int tile = blockIdx.x & 15;
  const int tid  = threadIdx.x;
  const int lane = tid & 63;
  const int wv   = tid >> 6;
  __shared__ float2 lds[16*258];
  __shared__ float2 V[2][32];
  __shared__ float red[4];
  if (tid < (FINAL ? 8 : 16)){
    int set = tid >> 3, j = tid & 7;
    float xv = x[(b0 + bb)*32 + t1 + set];
    float cc = sqrtf(0.5f*(1.f+xv));            // cos(arccos(x)/2)
    float sn = sqrtf(0.5f*(1.f-xv));
    float2 g00=G[j*4+0], g01=G[j*4+1], g10=G[j*4+2], g11=G[j*4+3];
    V[set][j*4+0] = cadd(cscale( cc,g00), cscale(sn,g01));
    V[set][j*4+1] = cadd(cscale(-sn,g00), cscale(cc,g01));
    V[set][j*4+2] = cadd(cscale( cc,g10), cscale(sn,g11));
    V[set][j*4+3] = cadd(cscale(-sn,g10), cscale(cc,g11));
  }
  float2* Sb = S + ((size_t)bb << 16);
  const float4* Sr = (const float4*)Sb;
  #pragma unroll
  for (int it=0; it<8; ++it){                   // stage in (2KB rows)
    int idx = it*256 + tid;
    int lp = idx & 127, dhi = idx >> 7;
    float4 v = Sr[(size_t)(tile*16 + dhi)*128 + lp];
    int c = swz(2*lp);
    lds[dhi*258 + c]     = make_float2(v.x, v.y);
    lds[dhi*258 + (c^1)] = make_float2(v.z, v.w);
  }
  __syncthreads();
  const int dh   = (wv<<2) | (lane>>4);
  const int g    = lane & 15;
  const int rowb = dh*258;
  float2 A[16];
  #pragma unroll
  for (int k=0;k<16;k++) A[k] = lds[rowb + swz(k + 16*g)];   // layout A
  { const float2* Vp = &V[0][0];                // A_t1 gates l0..l3
    gate16<1>(A, Vp[0], Vp[1], Vp[2], Vp[3]);
    gate16<2>(A, Vp[4], Vp[5], Vp[6], Vp[7]);
    gate16<4>(A, Vp[8], Vp[9], Vp[10],Vp[11]);
    gate16<8>(A, Vp[12],Vp[13],Vp[14],Vp[15]); }
  #pragma unroll
  for (int k=0;k<16;k++) lds[rowb + swz(k + 16*g)] = A[k];
  __syncthreads();
  #pragma unroll
  for (int k=0;k<16;k++) A[k] = lds[rowb + swz(g + 16*k)];   // layout B
  { const float2* Vp = &V[0][0];                // A_t1 gates l4..l7
    gate16<1>(A, Vp[16],Vp[17],Vp[18],Vp[19]);
    gate16<2>(A, Vp[20],Vp[21],Vp[22],Vp[23]);
    gate16<4>(A, Vp[24],Vp[25],Vp[26],Vp[27]);
    gate16<8>(A, Vp[28],Vp[29],Vp[30],Vp[31]); }
  if (!FINAL){
    // diagonal D: l = g + 16k; cls = bit0(l) | bit7(l)<<1 = (g&1) | (k>>3)<<1
    const int h = tile*16 + dh;
    float2 phb0 = PHB[(g&1)*256 + h];
    float2 phb1 = PHB[((g&1)|2)*256 + h];
    #pragma unroll
    for (int k=0;k<16;k++){
      float2 wk = cmul(PHL[g + 16*k], (k<8) ? phb0 : phb1);
      A[k] = cmul(A[k], wk);
    }
    { const float2* Vp = &V[1][0];              // A_{t1+1} gates l4..l7
      gate16<1>(A, Vp[16],Vp[17],Vp[18],Vp[19]);
      gate16<2>(A, Vp[20],Vp[21],Vp[22],Vp[23]);
      gate16<4>(A, Vp[24],Vp[25],Vp[26],Vp[27]);
      gate16<8>(A, Vp[28],Vp[29],Vp[30],Vp[31]); }
    #pragma unroll
    for (int k=0;k<16;k++) lds[rowb + swz(g + 16*k)] = A[k];
    __syncthreads();
    #pragma unroll
    for (int k=0;k<16;k++) A[k] = lds[rowb + swz(k + 16*g)]; // layout A
    { const float2* Vp = &V[1][0];              // A_{t1+1} gates l0..l3
      gate16<1>(A, Vp[0], Vp[1], Vp[2], Vp[3]);
      gate16<2>(A, Vp[4], Vp[5], Vp[6], Vp[7]);
      gate16<4>(A, Vp[8], Vp[9], Vp[10],Vp[11]);
      gate16<8>(A, Vp[12],Vp[13],Vp[14],Vp[15]); }
    #pragma unroll
    for (int k=0;k<16;k++) lds[rowb + swz(k + 16*g)] = A[k];
    __syncthreads();
    float4* Sw = (float4*)Sb;
    #pragma unroll
    for (int it=0; it<8; ++it){                 // stage out
      int idx = it*256 + tid;
      int lp = idx & 127, dhi = idx >> 7;
      int c = swz(2*lp);
      float2 v0 = lds[dhi*258 + c];
      float2 v1 = lds[dhi*258 + (c^1)];
      Sw[(size_t)(tile*16 + dhi)*128 + lp] = make_float4(v0.x,v0.y,v1.x,v1.y);
    }
  } else {
    // expectation: l = g + 16k; Q(l) = sum_j w_out[j]*(1-2 bit_j(l))
    float qg = 0.f;
    #pragma unroll
    for (int j=0;j<4;j++) qg += w_out[j] * (1.f - 2.f*(float)((g>>j)&1));
    float w4 = w_out[4], w5 = w_out[5], w6 = w_out[6], w7 = w_out[7];
    float acc = 0.f;
    #pragma unroll
    for (int k=0;k<16;k++){
      float qk = ((k&1)? -w4:w4) + ((k&2)? -w5:w5)
               + ((k&4)? -w6:w6) + ((k&8)? -w7:w7);
      acc += (qg + qk) * (A[k].x*A[k].x + A[k].y*A[k].y);
    }
    #pragma unroll
    for (int m=1;m<64;m<<=1) acc += __shfl_xor(acc, m, 64);
    if (lane == 0) red[wv] = acc;
    __syncthreads();
    if (tid == 0) atomicAdd(out + b0 + bb, red[0]+red[1]+red[2]+red[3]);
  }
}

// ---------- TypeH: B, D, B on high qubits ----------------------------------
// grid: bb = blockIdx>>4, lt = blockIdx&15. Tile in LDS: lds[dl][swz(h)].
// Thread (dl,g): layout A: h = k + 16g (in-thread h0-3); B: h = g + 16k.
// INIT builds (A_0 (x) B)|0> = Pl(l)*PH0[h] directly in layout B regs.
template<bool INIT>
__global__ __launch_bounds__(256, 4) void k_stepH(
    const float* __restrict__ x, const float2* __restrict__ G,
    const float2* __restrict__ PHL, const float2* __restrict__ PHB,
    const float2* __restrict__ PH0, float2* __restrict__ S, int b0){
  const int bb = blockIdx.x >> 4;
  const int lt = blockIdx.x & 15;
  const int l0 = lt*16;
  const int tid = threadIdx.x, lane = tid & 63, wv = tid >> 6;
  __shared__ float2 lds[16*258];
  __shared__ float2 V[32];
  const int dl   = (wv<<2) | (lane>>4);
  const int g    = lane & 15;
  const int rowb = dl*258;
  const float2* Gh = G + 32;
  float2 A[16];
  float2* Sb = S + ((size_t)bb << 16);
  if (INIT){
    if (tid < 8){
      int j = tid;
      float xv = x[(b0 + bb)*32 + 0];
      float cc = sqrtf(0.5f*(1.f+xv));
      float sn = sqrtf(0.5f*(1.f-xv));
      float2 g00=G[j*4+0], g01=G[j*4+1], g10=G[j*4+2], g11=G[j*4+3];
      V[j*4+0] = cadd(cscale(cc,g00), cscale(sn,g01));   // V[bit=0][0]
      V[j*4+2] = cadd(cscale(cc,g10), cscale(sn,g11));   // V[bit=1][0]
    }
    __syncthreads();
    const int l = l0 + dl;
    float2 Pl = make_float2(1.f, 0.f);
    #pragma unroll
    for (int j=0;j<8;j++) Pl = cmul(Pl, V[j*4 + 2*((l>>j)&1)]);
    const int cls = (l&1) | (((l>>7)&1)<<1);
    float2 phl = PHL[l];
    #pragma unroll
    for (int k=0;k<16;k++){                     // build in layout B + D
      float2 amp = cmul(Pl, PH0[g + 16*k]);
      A[k] = cmul(amp, cmul(phl, PHB[cls*256 + g + 16*k]));
    }
    gate16<1>(A, Gh[16],Gh[17],Gh[18],Gh[19]);  // h4..h7
    gate16<2>(A, Gh[20],Gh[21],Gh[22],Gh[23]);
    gate16<4>(A, Gh[24],Gh[25],Gh[26],Gh[27]);
    gate16<8>(A, Gh[28],Gh[29],Gh[30],Gh[31]);
    #pragma unroll
    for (int k=0;k<16;k++) lds[rowb + swz(g + 16*k)] = A[k];
    __syncthreads();
    #pragma unroll
    for (int k=0;k<16;k++) A[k] = lds[rowb + swz(k + 16*g)];
    gate16<1>(A, Gh[0], Gh[1], Gh[2], Gh[3]);   // h0..h3
    gate16<2>(A, Gh[4], Gh[5], Gh[6], Gh[7]);
    gate16<4>(A, Gh[8], Gh[9], Gh[10],Gh[11]);
    gate16<8>(A, Gh[12],Gh[13],Gh[14],Gh[15]);
    #pragma unroll
    for (int k=0;k<16;k++) lds[rowb + swz(k + 16*g)] = A[k];
    __syncthreads();
  } else {
    const float4* Sr = (const float4*)Sb;
    #pragma unroll
    for (int it=0; it<8; ++it){                 // stage in (128B segments)
      int idx = it*256 + tid;
      int q = idx & 7, h = idx >> 3;
      float4 v = Sr[(size_t)h*128 + (l0>>1) + q];
      int c = swz(h);
      lds[(2*q)*258 + c]   = make_float2(v.x, v.y);
      lds[(2*q+1)*258 + c] = make_float2(v.z, v.w);
    }
    __syncthreads();
    #pragma unroll
    for (int k=0;k<16;k++) A[k] = lds[rowb + swz(k + 16*g)]; // layout A
    gate16<1>(A, Gh[0], Gh[1], Gh[2], Gh[3]);   // sweep1: h0..h3
    gate16<2>(A, Gh[4], Gh[5], Gh[6], Gh[7]);
    gate16<4>(A, Gh[8], Gh[9], Gh[10],Gh[11]);
    gate16<8>(A, Gh[12],Gh[13],Gh[14],Gh[15]);
    #pragma unroll
    for (int k=0;k<16;k++) lds[rowb + swz(k + 16*g)] = A[k];
    __syncthreads();
    #pragma unroll
    for (int k=0;k<16;k++) A[k] = lds[rowb + swz(g + 16*k)]; // layout B
    gate16<1>(A, Gh[16],Gh[17],Gh[18],Gh[19]);  // sweep1: h4..h7
    gate16<2>(A, Gh[20],Gh[21],Gh[22],Gh[23]);
    gate16<4>(A, Gh[24],Gh[25],Gh[26],Gh[27]);
    gate16<8>(A, Gh[28],Gh[29],Gh[30],Gh[31]);
    { // diagonal D: h = g + 16k
      const int l = l0 + dl;
      const int cls = (l&1) | (((l>>7)&1)<<1);
      float2 phl = PHL[l];
      #pragma unroll
      for (int k=0;k<16;k++)
        A[k] = cmul(A[k], cmul(phl, PHB[cls*256 + g + 16*k]));
    }
    gate16<1>(A, Gh[16],Gh[17],Gh[18],Gh[19]);  // sweep2: h4..h7
    gate16<2>(A, Gh[20],Gh[21],Gh[22],Gh[23]);
    gate16<4>(A, Gh[24],Gh[25],Gh[26],Gh[27]);
    gate16<8>(A, Gh[28],Gh[29],Gh[30],Gh[31]);
    #pragma unroll
    for (int k=0;k<16;k++) lds[rowb + swz(g + 16*k)] = A[k];
    __syncthreads();
    #pragma unroll
    for (int k=0;k<16;k++) A[k] = lds[rowb + swz(k + 16*g)]; // layout A
    gate16<1>(A, Gh[0], Gh[1], Gh[2], Gh[3]);   // sweep2: h0..h3
    gate16<2>(A, Gh[4], Gh[5], Gh[6], Gh[7]);
    gate16<4>(A, Gh[8], Gh[9], Gh[10],Gh[11]);
    gate16<8>(A, Gh[12],Gh[13],Gh[14],Gh[15]);
    #pragma unroll
    for (int k=0;k<16;k++) lds[rowb + swz(k + 16*g)] = A[k];
    __syncthreads();
  }
  float4* Sw = (float4*)Sb;
  #pragma unroll
  for (int it=0; it<8; ++it){                   // stage out
    int idx = it*256 + tid;
    int q = idx & 7, h = idx >> 3;
    int c = swz(h);
    float2 v0 = lds[(2*q)*258 + c];
    float2 v1 = lds[(2*q+1)*258 + c];
    Sw[(size_t)h*128 + (l0>>1) + q] = make_float4(v0.x,v0.y,v1.x,v1.y);
  }
}

extern "C" void kernel_launch(void* const* d_in, const int* in_sizes, int n_in,
                              void* d_out, int out_size, void* d_ws, size_t ws_size,
                              hipStream_t stream){
  const float* x     = (const float*)d_in[0];   // [256,32]
  const float* w     = (const float*)d_in[1];   // [16,4]
  const float* w_out = (const float*)d_in[2];   // [1,8]
  const float* b_out = (const float*)d_in[3];   // [1]
  float* out = (float*)d_out;                   // [256]

  const size_t S_BYTES = (size_t)128 * 65536 * sizeof(float2);  // 64 MB chunk
  const size_t NEED = S_BYTES + (64+256+1024+256)*sizeof(float2);
  if (ws_size < NEED) return;

  float2* S   = (float2*)d_ws;
  float2* G   = (float2*)((char*)d_ws + S_BYTES);  // 64 entries
  float2* PHL = G + 64;                            // 256 entries
  float2* PHB = PHL + 256;                         // 1024 entries
  float2* PH0 = PHB + 1024;                        // 256 entries

  k_setup<<<1,256,0,stream>>>(w, b_out, out, G, PHL, PHB, PH0);
  for (int c=0;c<2;c++){
    const int b0 = c*128;
    k_stepH<true><<<2048,256,0,stream>>>(x, G, PHL, PHB, PH0, S, b0);
    for (int m=0;m<15;m++){
      k_stepL<false><<<2048,256,0,stream>>>(x, G, PHL, PHB, w_out, S, out, 2*m+1, b0);
      k_stepH<false><<<2048,256,0,stream>>>(x, G, PHL, PHB, PH0, S, b0);
    }
    k_stepL<true><<<2048,256,0,stream>>>(x, G, PHL, PHB, w_out, S, out, 31, b0);
  }
}

// Round 11
// 3913.016 us; speedup vs baseline: 1.1765x; 1.0763x over previous
//
#include <hip/hip_runtime.h>
#include <hip/hip_bf16.h>
#include <math.h>

// QRNN quantum-circuit simulator, 16 qubits, B=256, T=32.
// State: float2 S[bb][s], s = h*256 + l; qubit j<8 <-> bit j of l, qubit
// 8+k <-> bit k of h. bb = batch within the current 128-batch chunk (two
// chunks reuse the same 64MB workspace -> L3-resident).
//
// Schedule (verified r6/r8/r10):
//   H<INIT>: build (A_0 (x) B)|0>, D, B
//   L_m:     A_{2m+1}, D, A_{2m+2}     (m=0..14)
//   H:       B, D, B
//   L<FIN>:  A_31, expectation -> out
//
// HYBRID of measured-best halves:
//  - stepL: r8 structure (no LDS; 8 amps over 2 h-blocks; shfl-based apply8_2;
//    runtime nrep so only one V gate-set is live -> VGPR<=128). Measured ~45us.
//  - stepH: r10 structure (16 amps/thread register-local gates; XOR-swizzled
//    LDS transpose at the b64 bank floor). Measured ~52us (vs 65us shfl).
//  - Both: bb = blockIdx>>4 (l/h tiles of one batch adjacent -> L2 locality;
//    r9 showed the reversed mapping costs 2.5x traffic).

#define DEV static __device__ __forceinline__

DEV float2 cmul(float2 a, float2 b){ return make_float2(a.x*b.x - a.y*b.y, a.x*b.y + a.y*b.x); }
DEV float2 cadd(float2 a, float2 b){ return make_float2(a.x+b.x, a.y+b.y); }
DEV float2 cscale(float s, float2 a){ return make_float2(s*a.x, s*a.y); }
DEV float2 cfma2(float2 u0, float2 a, float2 u1, float2 b){
  return make_float2(u0.x*a.x - u0.y*a.y + u1.x*b.x - u1.y*b.y,
                     u0.x*a.y + u0.y*a.x + u1.x*b.y + u1.y*b.x);
}
DEV float2 shx(float2 v, int m){
  return make_float2(__shfl_xor(v.x, m, 64), __shfl_xor(v.y, m, 64));
}
DEV void gpair(float2 &A, float2 &B, float2 u00, float2 u01, float2 u10, float2 u11){
  float2 na = cfma2(u00, A, u01, B);
  float2 nb = cfma2(u10, A, u11, B);
  A = na; B = nb;
}
// XOR swizzle: bijective column for value v in 0..255 (stepH LDS)
DEV int swz(int v){ return v ^ ((v >> 4) & 15); }

// gate on in-thread bit B of a 16-amp register array (stepH)
template<int B>
DEV void gate16(float2* A, float2 u00, float2 u01, float2 u10, float2 u11){
  #pragma unroll
  for (int i=0;i<16;i++)
    if ((i & B) == 0) gpair(A[i], A[i|B], u00, u01, u10, u11);
}

// Two 256-amp slices (8 amps), stages interleaved (stepL; r8-verified).
// Local index n: bit0,bit7 in-thread; bits 1..6 = lane bits 0..5.
DEV void apply8_2(float2 &a0, float2 &a1, float2 &a2, float2 &a3,
                  float2 &b0, float2 &b1, float2 &b2, float2 &b3,
                  int lane, const float2* __restrict__ gm){
  gpair(a0,a1, gm[0],gm[1],gm[2],gm[3]);
  gpair(a2,a3, gm[0],gm[1],gm[2],gm[3]);
  gpair(b0,b1, gm[0],gm[1],gm[2],gm[3]);
  gpair(b2,b3, gm[0],gm[1],gm[2],gm[3]);
  #pragma unroll
  for (int k=1;k<=6;k++){
    const int m = 1<<(k-1);
    const bool hb = (lane>>(k-1)) & 1;
    float2 u00=gm[4*k+0], u01=gm[4*k+1], u10=gm[4*k+2], u11=gm[4*k+3];
    float2 cA = hb? u11:u00;
    float2 cP = hb? u10:u01;
    a0 = cfma2(cA,a0,cP,shx(a0,m));
    a1 = cfma2(cA,a1,cP,shx(a1,m));
    a2 = cfma2(cA,a2,cP,shx(a2,m));
    a3 = cfma2(cA,a3,cP,shx(a3,m));
    b0 = cfma2(cA,b0,cP,shx(b0,m));
    b1 = cfma2(cA,b1,cP,shx(b1,m));
    b2 = cfma2(cA,b2,cP,shx(b2,m));
    b3 = cfma2(cA,b3,cP,shx(b3,m));
  }
  gpair(a0,a2, gm[28],gm[29],gm[30],gm[31]);
  gpair(a1,a3, gm[28],gm[29],gm[30],gm[31]);
  gpair(b0,b2, gm[28],gm[29],gm[30],gm[31]);
  gpair(b1,b3, gm[28],gm[29],gm[30],gm[31]);
}

// ---------- setup: fused gates G_j, diagonal tables, B|0> table, out init ----
__global__ __launch_bounds__(256) void k_setup(
    const float* __restrict__ w, const float* __restrict__ b_out,
    float* __restrict__ out, float2* __restrict__ G,
    float2* __restrict__ PHL, float2* __restrict__ PHB,
    float2* __restrict__ PH0){
  __shared__ float2 Gs[64];
  int tid = threadIdx.x;
  if (tid < 16){
    int j = tid;
    float a0 = w[j*4+0], a1 = w[j*4+1], a2 = w[j*4+2];
    float c0 = cosf(0.5f*a0), s0 = sinf(0.5f*a0);
    float c1 = cosf(0.5f*a1), s1 = sinf(0.5f*a1);
    float c2 = cosf(0.5f*a2), s2 = sinf(0.5f*a2);
    float2 m00 = make_float2( c0*c1, -c0*s1);   // M = RZ(a1)*RX(a0)
    float2 m01 = make_float2(-s0*s1, -s0*c1);
    float2 m10 = make_float2( s0*s1, -s0*c1);
    float2 m11 = make_float2( c0*c1,  c0*s1);
    float2 mi2 = make_float2(0.f, -s2);
    float2 g0 = cadd(cscale(c2,m00), cmul(mi2,m10));   // G = RX(a2)*M
    float2 g1 = cadd(cscale(c2,m01), cmul(mi2,m11));
    float2 g2 = cadd(cmul(mi2,m00), cscale(c2,m10));
    float2 g3 = cadd(cmul(mi2,m01), cscale(c2,m11));
    Gs[j*4+0]=g0; Gs[j*4+1]=g1; Gs[j*4+2]=g2; Gs[j*4+3]=g3;
    G[j*4+0]=g0;  G[j*4+1]=g1;  G[j*4+2]=g2;  G[j*4+3]=g3;
  }
  __syncthreads();
  { // PHL[l]: chain edges (0,1)..(6,7), weight w[j+1,3]
    int l = tid; float phi = 0.f;
    for (int j=0;j<7;j++){
      float v = w[(j+1)*4+3];
      int u = ((l>>j)^(l>>(j+1)))&1;
      phi += -0.5f*v*(1.f-2.f*(float)u);
    }
    PHL[l] = make_float2(cosf(phi), sinf(phi));
  }
  // PHB[c][h]: edges (8,9)..(14,15) + cross (7,8)[w8] and (15,0)[w0];
  // c = bit0(l) | bit7(l)<<1
  for (int c=0;c<4;c++){
    int h = tid;
    float z0 = 1.f-2.f*(float)(c&1);
    float z7 = 1.f-2.f*(float)((c>>1)&1);
    float phi = 0.f;
    for (int k=0;k<7;k++){
      float v = w[(9+k)*4+3];
      int u = ((h>>k)^(h>>(k+1)))&1;
      phi += -0.5f*v*(1.f-2.f*(float)u);
    }
    phi += -0.5f*w[8*4+3]*z7*(1.f-2.f*(float)(h&1));
    phi += -0.5f*w[0*4+3]*(1.f-2.f*(float)((h>>7)&1))*z0;
    PHB[c*256+h] = make_float2(cosf(phi), sinf(phi));
  }
  { // PH0[h] = amplitude of B|0>_high at h
    float2 p = make_float2(1.f, 0.f);
    #pragma unroll
    for (int k=0;k<8;k++) p = cmul(p, Gs[(8+k)*4 + 2*((tid>>k)&1)]);
    PH0[tid] = p;
  }
  out[tid] = b_out[0];
}

// ---------- TypeL: A_t1 [, D, A_{t1+1}] on low qubits (r8 structure) -------
// grid = 128 bb * 16 tiles; 4 waves/block; 2 iters * 2 h-blocks (8 amps).
// nrep runtime (mid=2, FINAL=1) -> rep loop can't unroll -> one V set live.
template<bool FINAL>
__global__ __launch_bounds__(256, 4) void k_stepL(
    const float* __restrict__ x, const float2* __restrict__ G,
    const float2* __restrict__ PHL, const float2* __restrict__ PHB,
    const float* __restrict__ w_out, float2* __restrict__ S,
    float* __restrict__ out, int t1, int b0, int nrep){
  const int bb   = blockIdx.x >> 4;
  const int tile = blockIdx.x & 15;
  const int lane = threadIdx.x & 63;
  const int wv   = threadIdx.x >> 6;
  __shared__ float2 V[2][32];                  // fused V_j = G_j * Ry(x_t)
  __shared__ float red[4];
  if (threadIdx.x < (FINAL ? 8 : 16)){
    int set = threadIdx.x >> 3, j = threadIdx.x & 7;
    float xv = x[(b0 + bb)*32 + t1 + set];
    float cc = sqrtf(0.5f*(1.f+xv));           // cos(arccos(x)/2)
    float sn = sqrtf(0.5f*(1.f-xv));
    float2 g00=G[j*4+0], g01=G[j*4+1], g10=G[j*4+2], g11=G[j*4+3];
    V[set][j*4+0] = cadd(cscale( cc,g00), cscale(sn,g01));
    V[set][j*4+1] = cadd(cscale(-sn,g00), cscale(cc,g01));
    V[set][j*4+2] = cadd(cscale( cc,g10), cscale(sn,g11));
    V[set][j*4+3] = cadd(cscale(-sn,g10), cscale(cc,g11));
  }
  __syncthreads();
  float acc = 0.f;
  #pragma unroll 1
  for (int it=0; it<2; ++it){
    const int hb = tile*16 + wv*4 + it*2;      // two consecutive h-blocks
    float2* blk = S + (((size_t)bb)<<16) + (size_t)hb*256;
    const float4* p4 = (const float4*)blk;
    float4 lo  = p4[lane];
    float4 hi  = p4[64+lane];
    float4 lo2 = p4[128+lane];
    float4 hi2 = p4[192+lane];
    float2 a0 = make_float2(lo.x,lo.y),  a1 = make_float2(lo.z,lo.w);
    float2 a2 = make_float2(hi.x,hi.y),  a3 = make_float2(hi.z,hi.w);
    float2 b0q= make_float2(lo2.x,lo2.y),b1 = make_float2(lo2.z,lo2.w);
    float2 b2 = make_float2(hi2.x,hi2.y),b3 = make_float2(hi2.z,hi2.w);
    #pragma unroll 1
    for (int rep=0; rep<nrep; ++rep){
      apply8_2(a0,a1,a2,a3, b0q,b1,b2,b3, lane, &V[rep][0]);
      if (!FINAL && rep==0){
        // diagonal D: amps 0..3 carry (l0,l7)=(0,0),(1,0),(0,1),(1,1) -> c=0..3
        float2 sA0=PHB[0*256+hb],   sA1=PHB[1*256+hb];
        float2 sA2=PHB[2*256+hb],   sA3=PHB[3*256+hb];     // wave-uniform
        float2 sB0=PHB[0*256+hb+1], sB1=PHB[1*256+hb+1];
        float2 sB2=PHB[2*256+hb+1], sB3=PHB[3*256+hb+1];
        const float4* q4 = (const float4*)PHL;
        float4 plo = q4[lane];                 // PHL[2L], PHL[2L+1]
        float4 phi = q4[64+lane];              // PHL[128+2L], PHL[129+2L]
        float2 pl0 = make_float2(plo.x,plo.y), pl1 = make_float2(plo.z,plo.w);
        float2 ph2 = make_float2(phi.x,phi.y), ph3 = make_float2(phi.z,phi.w);
        a0 = cmul(a0, cmul(pl0, sA0));
        a1 = cmul(a1, cmul(pl1, sA1));
        a2 = cmul(a2, cmul(ph2, sA2));
        a3 = cmul(a3, cmul(ph3, sA3));
        b0q= cmul(b0q,cmul(pl0, sB0));
        b1 = cmul(b1, cmul(pl1, sB1));
        b2 = cmul(b2, cmul(ph2, sB2));
        b3 = cmul(b3, cmul(ph3, sB3));
      }
    }
    if (!FINAL){
      float4* o4 = (float4*)blk;
      o4[lane]     = make_float4(a0.x,a0.y,a1.x,a1.y);
      o4[64+lane]  = make_float4(a2.x,a2.y,a3.x,a3.y);
      o4[128+lane] = make_float4(b0q.x,b0q.y,b1.x,b1.y);
      o4[192+lane] = make_float4(b2.x,b2.y,b3.x,b3.y);
    } else {
      // expectation: Q(l) = sum_j w_out[j]*(1-2 bit_j(l)); data qubits = l bits
      float w0 = w_out[0], w7 = w_out[7];
      float qlane = 0.f;
      #pragma unroll
      for (int j=1;j<7;j++) qlane += w_out[j] * (1.f - 2.f*(float)((lane>>(j-1))&1));
      acc += (qlane + w0 + w7) * (a0.x*a0.x + a0.y*a0.y);
      acc += (qlane - w0 + w7) * (a1.x*a1.x + a1.y*a1.y);
      acc += (qlane + w0 - w7) * (a2.x*a2.x + a2.y*a2.y);
      acc += (qlane - w0 - w7) * (a3.x*a3.x + a3.y*a3.y);
      acc += (qlane + w0 + w7) * (b0q.x*b0q.x + b0q.y*b0q.y);
      acc += (qlane - w0 + w7) * (b1.x*b1.x + b1.y*b1.y);
      acc += (qlane + w0 - w7) * (b2.x*b2.x + b2.y*b2.y);
      acc += (qlane - w0 - w7) * (b3.x*b3.x + b3.y*b3.y);
    }
  }
  if (FINAL){
    #pragma unroll
    for (int m=1;m<64;m<<=1) acc += __shfl_xor(acc, m, 64);
    if (lane == 0) red[wv] = acc;
    __syncthreads();
    if (threadIdx.x == 0) atomicAdd(out + b0 + bb, red[0]+red[1]+red[2]+red[3]);
  }
}

// ---------- TypeH: B, D, B on high qubits (r10 structure) -------------------
// grid: bb = blockIdx>>4, lt = blockIdx&15. Tile in LDS: lds[dl][swz(h)].
// Thread (dl,g): layout A: h = k + 16g (in-thread h0-3); B: h = g + 16k.
// INIT builds (A_0 (x) B)|0> = Pl(l)*PH0[h] directly in layout B regs.
template<bool INIT>
__global__ __launch_bounds__(256, 4) void k_stepH(
    const float* __restrict__ x, const float2* __restrict__ G,
    const float2* __restrict__ PHL, const float2* __restrict__ PHB,
    const float2* __restrict__ PH0, float2* __restrict__ S, int b0){
  const int bb = blockIdx.x >> 4;
  const int lt = blockIdx.x & 15;
  const int l0 = lt*16;
  const int tid = threadIdx.x, lane = tid & 63, wv = tid >> 6;
  __shared__ float2 lds[16*258];
  __shared__ float2 V[32];
  const int dl   = (wv<<2) | (lane>>4);
  const int g    = lane & 15;
  const int rowb = dl*258;
  const float2* Gh = G + 32;
  float2 A[16];
  float2* Sb = S + ((size_t)bb << 16);
  if (INIT){
    if (tid < 8){
      int j = tid;
      float xv = x[(b0 + bb)*32 + 0];
      float cc = sqrtf(0.5f*(1.f+xv));
      float sn = sqrtf(0.5f*(1.f-xv));
      float2 g00=G[j*4+0], g01=G[j*4+1], g10=G[j*4+2], g11=G[j*4+3];
      V[j*4+0] = cadd(cscale(cc,g00), cscale(sn,g01));   // V[bit=0][0]
      V[j*4+2] = cadd(cscale(cc,g10), cscale(sn,g11));   // V[bit=1][0]
    }
    __syncthreads();
    const int l = l0 + dl;
    float2 Pl = make_float2(1.f, 0.f);
    #pragma unroll
    for (int j=0;j<8;j++) Pl = cmul(Pl, V[j*4 + 2*((l>>j)&1)]);
    const int cls = (l&1) | (((l>>7)&1)<<1);
    float2 phl = PHL[l];
    #pragma unroll
    for (int k=0;k<16;k++){                     // build in layout B + D
      float2 amp = cmul(Pl, PH0[g + 16*k]);
      A[k] = cmul(amp, cmul(phl, PHB[cls*256 + g + 16*k]));
    }
    gate16<1>(A, Gh[16],Gh[17],Gh[18],Gh[19]);  // h4..h7
    gate16<2>(A, Gh[20],Gh[21],Gh[22],Gh[23]);
    gate16<4>(A, Gh[24],Gh[25],Gh[26],Gh[27]);
    gate16<8>(A, Gh[28],Gh[29],Gh[30],Gh[31]);
    #pragma unroll
    for (int k=0;k<16;k++) lds[rowb + swz(g + 16*k)] = A[k];
    __syncthreads();
    #pragma unroll
    for (int k=0;k<16;k++) A[k] = lds[rowb + swz(k + 16*g)];
    gate16<1>(A, Gh[0], Gh[1], Gh[2], Gh[3]);   // h0..h3
    gate16<2>(A, Gh[4], Gh[5], Gh[6], Gh[7]);
    gate16<4>(A, Gh[8], Gh[9], Gh[10],Gh[11]);
    gate16<8>(A, Gh[12],Gh[13],Gh[14],Gh[15]);
    #pragma unroll
    for (int k=0;k<16;k++) lds[rowb + swz(k + 16*g)] = A[k];
    __syncthreads();
  } else {
    const float4* Sr = (const float4*)Sb;
    #pragma unroll
    for (int it=0; it<8; ++it){                 // stage in (128B segments)
      int idx = it*256 + tid;
      int q = idx & 7, h = idx >> 3;
      float4 v = Sr[(size_t)h*128 + (l0>>1) + q];
      int c = swz(h);
      lds[(2*q)*258 + c]   = make_float2(v.x, v.y);
      lds[(2*q+1)*258 + c] = make_float2(v.z, v.w);
    }
    __syncthreads();
    #pragma unroll
    for (int k=0;k<16;k++) A[k] = lds[rowb + swz(k + 16*g)]; // layout A
    gate16<1>(A, Gh[0], Gh[1], Gh[2], Gh[3]);   // sweep1: h0..h3
    gate16<2>(A, Gh[4], Gh[5], Gh[6], Gh[7]);
    gate16<4>(A, Gh[8], Gh[9], Gh[10],Gh[11]);
    gate16<8>(A, Gh[12],Gh[13],Gh[14],Gh[15]);
    #pragma unroll
    for (int k=0;k<16;k++) lds[rowb + swz(k + 16*g)] = A[k];
    __syncthreads();
    #pragma unroll
    for (int k=0;k<16;k++) A[k] = lds[rowb + swz(g + 16*k)]; // layout B
    gate16<1>(A, Gh[16],Gh[17],Gh[18],Gh[19]);  // sweep1: h4..h7
    gate16<2>(A, Gh[20],Gh[21],Gh[22],Gh[23]);
    gate16<4>(A, Gh[24],Gh[25],Gh[26],Gh[27]);
    gate16<8>(A, Gh[28],Gh[29],Gh[30],Gh[31]);
    { // diagonal D: h = g + 16k
      const int l = l0 + dl;
      const int cls = (l&1) | (((l>>7)&1)<<1);
      float2 phl = PHL[l];
      #pragma unroll
      for (int k=0;k<16;k++)
        A[k] = cmul(A[k], cmul(phl, PHB[cls*256 + g + 16*k]));
    }
    gate16<1>(A, Gh[16],Gh[17],Gh[18],Gh[19]);  // sweep2: h4..h7
    gate16<2>(A, Gh[20],Gh[21],Gh[22],Gh[23]);
    gate16<4>(A, Gh[24],Gh[25],Gh[26],Gh[27]);
    gate16<8>(A, Gh[28],Gh[29],Gh[30],Gh[31]);
    #pragma unroll
    for (int k=0;k<16;k++) lds[rowb + swz(g + 16*k)] = A[k];
    __syncthreads();
    #pragma unroll
    for (int k=0;k<16;k++) A[k] = lds[rowb + swz(k + 16*g)]; // layout A
    gate16<1>(A, Gh[0], Gh[1], Gh[2], Gh[3]);   // sweep2: h0..h3
    gate16<2>(A, Gh[4], Gh[5], Gh[6], Gh[7]);
    gate16<4>(A, Gh[8], Gh[9], Gh[10],Gh[11]);
    gate16<8>(A, Gh[12],Gh[13],Gh[14],Gh[15]);
    #pragma unroll
    for (int k=0;k<16;k++) lds[rowb + swz(k + 16*g)] = A[k];
    __syncthreads();
  }
  float4* Sw = (float4*)Sb;
  #pragma unroll
  for (int it=0; it<8; ++it){                   // stage out
    int idx = it*256 + tid;
    int q = idx & 7, h = idx >> 3;
    int c = swz(h);
    float2 v0 = lds[(2*q)*258 + c];
    float2 v1 = lds[(2*q+1)*258 + c];
    Sw[(size_t)h*128 + (l0>>1) + q] = make_float4(v0.x,v0.y,v1.x,v1.y);
  }
}

extern "C" void kernel_launch(void* const* d_in, const int* in_sizes, int n_in,
                              void* d_out, int out_size, void* d_ws, size_t ws_size,
                              hipStream_t stream){
  const float* x     = (const float*)d_in[0];   // [256,32]
  const float* w     = (const float*)d_in[1];   // [16,4]
  const float* w_out = (const float*)d_in[2];   // [1,8]
  const float* b_out = (const float*)d_in[3];   // [1]
  float* out = (float*)d_out;                   // [256]

  const size_t S_BYTES = (size_t)128 * 65536 * sizeof(float2);  // 64 MB chunk
  const size_t NEED = S_BYTES + (64+256+1024+256)*sizeof(float2);
  if (ws_size < NEED) return;

  float2* S   = (float2*)d_ws;
  float2* G   = (float2*)((char*)d_ws + S_BYTES);  // 64 entries
  float2* PHL = G + 64;                            // 256 entries
  float2* PHB = PHL + 256;                         // 1024 entries
  float2* PH0 = PHB + 1024;                        // 256 entries

  k_setup<<<1,256,0,stream>>>(w, b_out, out, G, PHL, PHB, PH0);
  for (int c=0;c<2;c++){
    const int b0 = c*128;
    k_stepH<true><<<2048,256,0,stream>>>(x, G, PHL, PHB, PH0, S, b0);
    for (int m=0;m<15;m++){
      k_stepL<false><<<2048,256,0,stream>>>(x, G, PHL, PHB, w_out, S, out, 2*m+1, b0, 2);
      k_stepH<false><<<2048,256,0,stream>>>(x, G, PHL, PHB, PH0, S, b0);
    }
    k_stepL<true><<<2048,256,0,stream>>>(x, G, PHL, PHB, w_out, S, out, 31, b0, 1);
  }
}